// Round 4
// baseline (393.912 us; speedup 1.0000x reference)
//
#include <hip/hip_runtime.h>
#include <hip/hip_bf16.h>

#define EMBED 512
#define NSEQ 2048
#define NROWS 4096
#define QKV_STRIDE 1536
#define NBLK 768

typedef unsigned short u16;
typedef __bf16 bf16x8 __attribute__((ext_vector_type(8)));
typedef float f32x4 __attribute__((ext_vector_type(4)));

__device__ __forceinline__ u16 f2bf(float f) {
    unsigned u = __float_as_uint(f);
    unsigned r = (u + 0x7FFFu + ((u >> 16) & 1u)) >> 16;
    return (u16)r;
}

#define XELEMS    (NROWS * EMBED)     // 2097152
#define WCATELEMS (1536 * EMBED)      // 786432
#define WOELEMS   (EMBED * EMBED)     // 262144

// ---------------------------------------------------------------------------
// prep: fp32 -> bf16 conversions + zero the grid-barrier counters.
// ---------------------------------------------------------------------------
__global__ __launch_bounds__(256) void prep_kernel(
    const float* __restrict__ x,
    const float* __restrict__ Wq, const float* __restrict__ Wk,
    const float* __restrict__ Wv, const float* __restrict__ Wo,
    u16* __restrict__ xb, u16* __restrict__ Wcat, u16* __restrict__ Wob,
    unsigned* __restrict__ bar)
{
    if (blockIdx.x == 0 && threadIdx.x < 2) bar[threadIdx.x] = 0;

    const long long e0 = (long long)(blockIdx.x * 256 + threadIdx.x) * 8;
    const float* src;
    u16* dst;
    if (e0 < XELEMS) {
        src = x + e0; dst = xb + e0;
    } else if (e0 < XELEMS + WCATELEMS) {
        const long long j = e0 - XELEMS;
        const int row = (int)(j >> 9);
        const int col = (int)(j & 511);
        const int sel = row >> 9;            // 0:Wq 1:Wk 2:Wv
        const int r   = row & 511;
        const float* W = (sel == 0) ? Wq : (sel == 1) ? Wk : Wv;
        src = W + (size_t)r * EMBED + col; dst = Wcat + j;
    } else {
        const long long j = e0 - XELEMS - WCATELEMS;
        src = Wo + j; dst = Wob + j;
    }
    float4 a = *(const float4*)(src);
    float4 b = *(const float4*)(src + 4);
    union { u16 u[8]; uint4 v; } p;
    p.u[0] = f2bf(a.x); p.u[1] = f2bf(a.y); p.u[2] = f2bf(a.z); p.u[3] = f2bf(a.w);
    p.u[4] = f2bf(b.x); p.u[5] = f2bf(b.y); p.u[6] = f2bf(b.z); p.u[7] = f2bf(b.w);
    *(uint4*)(dst) = p.v;
}

// ---------------------------------------------------------------------------
// software grid barrier (all NBLK blocks co-resident by construction:
// __launch_bounds__(256,3) -> VGPR<=168, LDS 12.9KB -> 3 blocks/CU x 256 CU).
// ---------------------------------------------------------------------------
__device__ __forceinline__ void grid_barrier(unsigned* ctr)
{
    __syncthreads();
    if (threadIdx.x == 0) {
        __threadfence();   // release: block's prior global writes -> device scope
        __hip_atomic_fetch_add(ctr, 1u, __ATOMIC_RELEASE, __HIP_MEMORY_SCOPE_AGENT);
        while (__hip_atomic_load(ctr, __ATOMIC_ACQUIRE, __HIP_MEMORY_SCOPE_AGENT) < NBLK)
            __builtin_amdgcn_s_sleep(8);
    }
    __syncthreads();
    __threadfence();       // acquire side for all threads (L1/L2 inv)
}

// ---------------------------------------------------------------------------
// 128x64 bf16 MFMA tile: C[m0:+128, n0:+64] = A @ W^T + bias(64).
// A,W k-major bf16 (lda=ldw=EMBED). Optional per-column-sum epilogue.
// ---------------------------------------------------------------------------
__device__ __forceinline__ void gemm_tile_128x64(
    u16* __restrict__ As, u16* __restrict__ Bs, float (*csum)[64],
    const u16* __restrict__ A, const u16* __restrict__ W,
    const float* __restrict__ bias,
    float* __restrict__ C, int ldc, int m0, int n0,
    float* __restrict__ vpartial, int mblock)
{
    const int t    = threadIdx.x;
    const int wave = t >> 6, lane = t & 63;
    const int wm   = wave >> 1, wn = wave & 1;
    const int qd   = lane >> 4, lr = lane & 15;
    const int srow = t >> 2;
    const int sk   = (t & 3) * 8;

    f32x4 acc[4][2] = {};

    const u16* Ag = A + (size_t)m0 * EMBED;
    const u16* Wg = W + (size_t)n0 * EMBED;

    u16* AsW0 = As + (size_t)(wave * 64) * 8;          // rows 0..63
    u16* AsW1 = As + (size_t)(256 + wave * 64) * 8;    // rows 64..127
    u16* BsW0 = Bs + (size_t)(wave * 64) * 8;          // rows 0..63

    for (int kc = 0; kc < EMBED; kc += 32) {
        __builtin_amdgcn_global_load_lds(
            (const __attribute__((address_space(1))) void*)(Ag + (size_t)srow * EMBED + kc + sk),
            (__attribute__((address_space(3))) void*)AsW0, 16, 0, 0);
        __builtin_amdgcn_global_load_lds(
            (const __attribute__((address_space(1))) void*)(Ag + (size_t)(srow + 64) * EMBED + kc + sk),
            (__attribute__((address_space(3))) void*)AsW1, 16, 0, 0);
        __builtin_amdgcn_global_load_lds(
            (const __attribute__((address_space(1))) void*)(Wg + (size_t)srow * EMBED + kc + sk),
            (__attribute__((address_space(3))) void*)BsW0, 16, 0, 0);
        __syncthreads();

        bf16x8 af[4], bfr[2];
#pragma unroll
        for (int i = 0; i < 4; ++i)
            af[i]  = *(const bf16x8*)&As[(wm * 64 + i * 16 + lr) * 32 + qd * 8];
#pragma unroll
        for (int i = 0; i < 2; ++i)
            bfr[i] = *(const bf16x8*)&Bs[(wn * 32 + i * 16 + lr) * 32 + qd * 8];
#pragma unroll
        for (int mi = 0; mi < 4; ++mi)
#pragma unroll
            for (int ni = 0; ni < 2; ++ni)
                acc[mi][ni] = __builtin_amdgcn_mfma_f32_16x16x32_bf16(
                    af[mi], bfr[ni], acc[mi][ni], 0, 0, 0);
        __syncthreads();
    }

    // C/D layout: col=lane&15, row=(lane>>4)*4+reg
#pragma unroll
    for (int ni = 0; ni < 2; ++ni) {
        const int cl = wn * 32 + ni * 16 + lr;
        const float bb = bias[cl];
#pragma unroll
        for (int mi = 0; mi < 4; ++mi) {
#pragma unroll
            for (int e = 0; e < 4; ++e) {
                const int row = m0 + wm * 64 + mi * 16 + qd * 4 + e;
                C[(size_t)row * ldc + n0 + cl] = acc[mi][ni][e] + bb;
            }
        }
    }

    if (vpartial) {
#pragma unroll
        for (int ni = 0; ni < 2; ++ni) {
            float s = 0.f;
#pragma unroll
            for (int mi = 0; mi < 4; ++mi)
#pragma unroll
                for (int e = 0; e < 4; ++e) s += acc[mi][ni][e];
            s += __shfl_xor(s, 16);
            s += __shfl_xor(s, 32);
            if (qd == 0) csum[wm][wn * 32 + ni * 16 + lr] = s;
        }
        __syncthreads();
        if (t < 64)
            vpartial[(size_t)t * 32 + mblock] = csum[0][t] + csum[1][t];
        __syncthreads();
    }
}

// ---------------------------------------------------------------------------
// mega: QKV gemm -> barrier -> attention -> barrier -> output gemm.
// ---------------------------------------------------------------------------
__global__ __launch_bounds__(256, 3) void mega_kernel(
    const u16* __restrict__ xb, const u16* __restrict__ Wcat,
    const u16* __restrict__ Wob,
    const float* __restrict__ bq, const float* __restrict__ bk,
    const float* __restrict__ bv, const float* __restrict__ bo,
    float* __restrict__ QKV, float* __restrict__ vpart2,
    u16* __restrict__ AOb, float* __restrict__ out,
    unsigned* __restrict__ bar)
{
    __shared__ __align__(16) u16 As[128 * 32];
    __shared__ __align__(16) u16 Bs[64 * 32];
    __shared__ float csum[2][64];

    // ---- phase 1: QKV gemm, 768 tiles of 128x64, exactly one per block
    {
        const int m0 = (blockIdx.x & 31) * 128;
        const int n0 = (blockIdx.x >> 5) * 64;         // 0..1472
        const int sel = n0 >> 9;
        const float* bias = ((sel == 0) ? bq : (sel == 1) ? bk : bv) + (n0 & 511);
        float* vp = (sel == 2) ? (vpart2 + (size_t)(n0 - 1024) * 32) : nullptr;
        gemm_tile_128x64(As, Bs, csum, xb, Wcat, bias, QKV, QKV_STRIDE,
                         m0, n0, vp, m0 >> 7);
    }
    grid_barrier(bar + 0);

    // ---- phase 2: attention, 8192 wave-tasks over 3072 waves
    {
        const int wave = threadIdx.x >> 6, lane = threadIdx.x & 63;
        const int gw = blockIdx.x * 4 + wave;
        for (int task = gw; task < 8192; task += NBLK * 4) {
            const int bh = task >> 9;
            const int r0 = (task & 511) * 4;
            const int b = bh >> 3, h = bh & 7;

            const float* Qb = QKV + (size_t)(b * NSEQ) * QKV_STRIDE + h * 64;
            const float* Kb = Qb + 512;
            const float* Vb = Qb + 1024;

            const float v0 = Vb[(size_t)0 * QKV_STRIDE + lane];
            const float v1 = Vb[(size_t)1 * QKV_STRIDE + lane];
            const float v2 = Vb[(size_t)2 * QKV_STRIDE + lane];

            const int c = h * 64 + lane;
            float vs = 0.f;
#pragma unroll
            for (int mb = 0; mb < 16; ++mb)
                vs += vpart2[(size_t)c * 32 + b * 16 + mb];
            vs += (float)NSEQ * bv[c];
            vs -= (v0 + v1 + v2);

            u16* AObh = AOb + (size_t)(b * NSEQ) * EMBED + h * 64;
#pragma unroll
            for (int i = 0; i < 4; ++i) {
                const int r = r0 + i;
                const float q  = Qb[(size_t)r * QKV_STRIDE + lane];
                const float km = Kb[(size_t)r * QKV_STRIDE + lane];
                const float kp = (r > 0)        ? Kb[(size_t)(r - 1) * QKV_STRIDE + lane] : 0.f;
                const float kn = (r < NSEQ - 1) ? Kb[(size_t)(r + 1) * QKV_STRIDE + lane] : 0.f;
                float s0 = q * kp, s1 = q * km, s2 = q * kn;
#pragma unroll
                for (int off = 32; off > 0; off >>= 1) {
                    s0 += __shfl_xor(s0, off);
                    s1 += __shfl_xor(s1, off);
                    s2 += __shfl_xor(s2, off);
                }
                const float m  = fmaxf(fmaxf(s0, s1), fmaxf(s2, 0.f));
                const float e0 = __expf(s0 - m);
                const float e1 = __expf(s1 - m);
                const float e2 = __expf(s2 - m);
                const float eb = __expf(-m);
                const float rd = 1.f / (e0 + e1 + e2 + (float)(NSEQ - 3) * eb);
                const float o  = (e0 * v0 + e1 * v1 + e2 * v2 + eb * vs) * rd;
                AObh[(size_t)r * EMBED + lane] = f2bf(o);
            }
        }
    }
    grid_barrier(bar + 1);

    // ---- phase 3: output gemm, 256 tiles of 128x64 on blocks 0..255
    if (blockIdx.x < 256) {
        const int m0 = (blockIdx.x >> 3) * 128;
        const int n0 = (blockIdx.x & 7) * 64;
        gemm_tile_128x64(As, Bs, csum, AOb, Wob, bo + n0, out, EMBED,
                         m0, n0, nullptr, 0);
    }
}

extern "C" void kernel_launch(void* const* d_in, const int* in_sizes, int n_in,
                              void* d_out, int out_size, void* d_ws, size_t ws_size,
                              hipStream_t stream)
{
    const float* x  = (const float*)d_in[0];
    const float* Wq = (const float*)d_in[1];
    const float* bq = (const float*)d_in[2];
    const float* Wk = (const float*)d_in[3];
    const float* bk = (const float*)d_in[4];
    const float* Wv = (const float*)d_in[5];
    const float* bv = (const float*)d_in[6];
    const float* Wo = (const float*)d_in[7];
    const float* bo = (const float*)d_in[8];
    float* out = (float*)d_out;

    float*   QKV    = (float*)d_ws;                              // 6291456 f
    u16*     xb     = (u16*)(QKV + (size_t)NROWS * QKV_STRIDE);  // 2097152 bf16
    u16*     AOb    = xb;                                        // alias (xb dead after phase 1)
    u16*     Wcat   = xb + XELEMS;                               // 786432
    u16*     Wob    = Wcat + WCATELEMS;                          // 262144
    float*   vpart2 = (float*)(Wob + WOELEMS);                   // 512*32 f
    unsigned* bar   = (unsigned*)(vpart2 + 512 * 32);            // 2 u32

    const int prep_blocks = (XELEMS + WCATELEMS + WOELEMS) / 8 / 256;  // 1536
    prep_kernel<<<prep_blocks, 256, 0, stream>>>(x, Wq, Wk, Wv, Wo, xb, Wcat, Wob, bar);
    mega_kernel<<<NBLK, 256, 0, stream>>>(xb, Wcat, Wob, bq, bk, bv, bo,
                                          QKV, vpart2, AOb, out, bar);
}

// Round 5
// 108.753 us; speedup vs baseline: 3.6221x; 3.6221x over previous
//
#include <hip/hip_runtime.h>
#include <hip/hip_bf16.h>

#define EMBED 512
#define NSEQ 2048
#define NROWS 4096
#define QKV_STRIDE 1536

typedef unsigned short u16;
typedef __bf16 bf16x8 __attribute__((ext_vector_type(8)));
typedef float f32x4 __attribute__((ext_vector_type(4)));

__device__ __forceinline__ u16 f2bf(float f) {
    unsigned u = __float_as_uint(f);
    unsigned r = (u + 0x7FFFu + ((u >> 16) & 1u)) >> 16;
    return (u16)r;
}

#define XELEMS    (NROWS * EMBED)     // 2097152
#define WCATELEMS (1536 * EMBED)      // 786432
#define NCONVB    1408                // (XELEMS+WCATELEMS)/8/256

// ---------------------------------------------------------------------------
// prep: x -> bf16, Wq|Wk|Wv -> Wcat bf16; init vs[b][c] = 2048*bv[c]
// (vs then accumulates per-batch V column sums via atomicAdd in gemm_qkv).
// ---------------------------------------------------------------------------
__global__ __launch_bounds__(256) void prep_kernel(
    const float* __restrict__ x,
    const float* __restrict__ Wq, const float* __restrict__ Wk,
    const float* __restrict__ Wv, const float* __restrict__ bv,
    u16* __restrict__ xb, u16* __restrict__ Wcat, float* __restrict__ vs)
{
    if (blockIdx.x == NCONVB) {
#pragma unroll
        for (int i = 0; i < 4; ++i) {
            const int idx = threadIdx.x + i * 256;     // 0..1023 = [b][c]
            vs[idx] = (float)NSEQ * bv[idx & 511];
        }
        return;
    }
    const long long e0 = (long long)(blockIdx.x * 256 + threadIdx.x) * 8;
    const float* src;
    u16* dst;
    if (e0 < XELEMS) {
        src = x + e0; dst = xb + e0;
    } else {
        const long long j = e0 - XELEMS;
        const int row = (int)(j >> 9);
        const int col = (int)(j & 511);
        const int sel = row >> 9;            // 0:Wq 1:Wk 2:Wv
        const int r   = row & 511;
        const float* W = (sel == 0) ? Wq : (sel == 1) ? Wk : Wv;
        src = W + (size_t)r * EMBED + col; dst = Wcat + j;
    }
    float4 a = *(const float4*)(src);
    float4 b = *(const float4*)(src + 4);
    union { u16 u[8]; uint4 v; } p;
    p.u[0] = f2bf(a.x); p.u[1] = f2bf(a.y); p.u[2] = f2bf(a.z); p.u[3] = f2bf(a.w);
    p.u[4] = f2bf(b.x); p.u[5] = f2bf(b.y); p.u[6] = f2bf(b.z); p.u[7] = f2bf(b.w);
    *(uint4*)(dst) = p.v;
}

// ---------------------------------------------------------------------------
// QKV GEMM: 768 blocks, one 128x64 bf16-MFMA tile each (3 exact CU rounds).
// Q,K tiles: full fp32 store (+bias). V tiles: store only rows 0..2 of each
// batch (+bias) and atomicAdd the pre-bias column sums into vs[batch][col].
// ---------------------------------------------------------------------------
__global__ __launch_bounds__(256) void gemm_qkv_mfma(
    const u16* __restrict__ A, const u16* __restrict__ W,
    const float* __restrict__ bq, const float* __restrict__ bk,
    const float* __restrict__ bvv, float* __restrict__ QKV,
    float* __restrict__ vs)
{
    __shared__ __align__(16) u16 As[128 * 32];
    __shared__ __align__(16) u16 Bs[64 * 32];

    const int m0 = (blockIdx.x & 31) * 128;
    const int n0 = (blockIdx.x >> 5) * 64;             // 0..1472
    const int sel = n0 >> 9;
    const float* bias = ((sel == 0) ? bq : (sel == 1) ? bk : bvv) + (n0 & 511);

    const int t    = threadIdx.x;
    const int wave = t >> 6, lane = t & 63;
    const int wm   = wave >> 1, wn = wave & 1;
    const int qd   = lane >> 4, lr = lane & 15;
    const int srow = t >> 2;
    const int sk   = (t & 3) * 8;

    f32x4 acc[4][2] = {};

    const u16* Ag = A + (size_t)m0 * EMBED;
    const u16* Wg = W + (size_t)n0 * EMBED;

    u16* AsW0 = As + (size_t)(wave * 64) * 8;
    u16* AsW1 = As + (size_t)(256 + wave * 64) * 8;
    u16* BsW0 = Bs + (size_t)(wave * 64) * 8;

    for (int kc = 0; kc < EMBED; kc += 32) {
        __builtin_amdgcn_global_load_lds(
            (const __attribute__((address_space(1))) void*)(Ag + (size_t)srow * EMBED + kc + sk),
            (__attribute__((address_space(3))) void*)AsW0, 16, 0, 0);
        __builtin_amdgcn_global_load_lds(
            (const __attribute__((address_space(1))) void*)(Ag + (size_t)(srow + 64) * EMBED + kc + sk),
            (__attribute__((address_space(3))) void*)AsW1, 16, 0, 0);
        __builtin_amdgcn_global_load_lds(
            (const __attribute__((address_space(1))) void*)(Wg + (size_t)srow * EMBED + kc + sk),
            (__attribute__((address_space(3))) void*)BsW0, 16, 0, 0);
        __syncthreads();

        bf16x8 af[4], bfr[2];
#pragma unroll
        for (int i = 0; i < 4; ++i)
            af[i]  = *(const bf16x8*)&As[(wm * 64 + i * 16 + lr) * 32 + qd * 8];
#pragma unroll
        for (int i = 0; i < 2; ++i)
            bfr[i] = *(const bf16x8*)&Bs[(wn * 32 + i * 16 + lr) * 32 + qd * 8];
#pragma unroll
        for (int mi = 0; mi < 4; ++mi)
#pragma unroll
            for (int ni = 0; ni < 2; ++ni)
                acc[mi][ni] = __builtin_amdgcn_mfma_f32_16x16x32_bf16(
                    af[mi], bfr[ni], acc[mi][ni], 0, 0, 0);
        __syncthreads();
    }

    // C/D layout: col=lane&15, row=(lane>>4)*4+reg
    if (sel < 2) {
#pragma unroll
        for (int ni = 0; ni < 2; ++ni) {
            const int cl = wn * 32 + ni * 16 + lr;
            const float bb = bias[cl];
#pragma unroll
            for (int mi = 0; mi < 4; ++mi)
#pragma unroll
                for (int e = 0; e < 4; ++e) {
                    const int row = m0 + wm * 64 + mi * 16 + qd * 4 + e;
                    QKV[(size_t)row * QKV_STRIDE + n0 + cl] = acc[mi][ni][e] + bb;
                }
        }
    } else {
        const int batch = m0 >> 11;     // tile never crosses batch (2048%128==0)
#pragma unroll
        for (int ni = 0; ni < 2; ++ni) {
            const int cl  = wn * 32 + ni * 16 + lr;
            const int col = n0 + cl;                 // 1024..1535
            const float bb = bias[cl];
            float s = 0.f;
#pragma unroll
            for (int mi = 0; mi < 4; ++mi)
#pragma unroll
                for (int e = 0; e < 4; ++e) {
                    const int row = m0 + wm * 64 + mi * 16 + qd * 4 + e;
                    s += acc[mi][ni][e];
                    if ((row & (NSEQ - 1)) < 3)
                        QKV[(size_t)row * QKV_STRIDE + col] = acc[mi][ni][e] + bb;
                }
            s += __shfl_xor(s, 16);
            s += __shfl_xor(s, 32);
            if (qd == 0)
                atomicAdd(&vs[batch * 512 + (col - 1024)], s);
        }
    }
}

// ---------------------------------------------------------------------------
// Wsmall: WT[b][j][s] (s=4h+t) = sum_{c in head h} Vsm[b][t][c] * Wo[j][c]
// Vsm rows: t=0,1,2 -> V rows 0..2 (biased, from QKV); t=3 -> tail sum
// vs[b][c] - (v0+v1+v2). Grid 128 blocks (2 batches x 64 j-groups of 8).
// ---------------------------------------------------------------------------
__global__ __launch_bounds__(256) void wsmall_kernel(
    const float* __restrict__ QKV, const float* __restrict__ vs,
    const float* __restrict__ Wo, float* __restrict__ WT)
{
    __shared__ float Vsm[4][512];
    const int b  = blockIdx.x >> 6;
    const int jb = blockIdx.x & 63;
    const int t  = threadIdx.x;

    const float* Vbase = QKV + (size_t)b * NSEQ * QKV_STRIDE + 1024;
    for (int idx = t; idx < 512; idx += 256) {
        const float v0 = Vbase[idx];
        const float v1 = Vbase[QKV_STRIDE + idx];
        const float v2 = Vbase[2 * QKV_STRIDE + idx];
        Vsm[0][idx] = v0; Vsm[1][idx] = v1; Vsm[2][idx] = v2;
        Vsm[3][idx] = vs[b * 512 + idx] - (v0 + v1 + v2);
    }
    __syncthreads();

    const int j  = jb * 8 + (t >> 5);
    const int s  = t & 31;
    const int h  = s >> 2, tt = s & 3;
    const float* Wor = Wo + (size_t)j * EMBED + h * 64;
    const float* vr  = &Vsm[tt][h * 64];
    float acc = 0.f;
#pragma unroll
    for (int c = 0; c < 64; ++c) {
        const int cc = (c + 2 * s) & 63;    // rotate to spread LDS banks
        acc = fmaf(vr[cc], Wor[cc], acc);
    }
    WT[((size_t)b * 512 + j) * 32 + s] = acc;
}

// ---------------------------------------------------------------------------
// Fused attention + K=32 output GEMM. Grid 256 blocks x 16 rows.
// Phase A: per row, all-head scores via 8-lane segmented reduction ->
// normalized coefs E[16][32] in LDS. Phase B: out = E @ WT^T + bo.
// ---------------------------------------------------------------------------
__global__ __launch_bounds__(256) void attn_out_kernel(
    const float* __restrict__ QKV, const float* __restrict__ WT,
    const float* __restrict__ bo, float* __restrict__ out)
{
    __shared__ float E[16][32];
    const int r0   = blockIdx.x * 16;
    const int b    = r0 >> 11;
    const int wave = threadIdx.x >> 6, lane = threadIdx.x & 63;
    const int d0   = lane * 8;

#pragma unroll
    for (int i = 0; i < 4; ++i) {
        const int rl = wave * 4 + i;
        const int r  = r0 + rl;
        const int sr = r & (NSEQ - 1);
        const float* Qr = QKV + (size_t)r * QKV_STRIDE + d0;
        const float* Kr = QKV + (size_t)r * QKV_STRIDE + 512 + d0;

        float4 qa = *(const float4*)(Qr);
        float4 qb = *(const float4*)(Qr + 4);
        float4 ka = *(const float4*)(Kr);
        float4 kb = *(const float4*)(Kr + 4);
        float s1 = qa.x*ka.x + qa.y*ka.y + qa.z*ka.z + qa.w*ka.w
                 + qb.x*kb.x + qb.y*kb.y + qb.z*kb.z + qb.w*kb.w;
        float s0 = 0.f, s2 = 0.f;
        if (sr > 0) {
            float4 pa = *(const float4*)(Kr - QKV_STRIDE);
            float4 pb = *(const float4*)(Kr - QKV_STRIDE + 4);
            s0 = qa.x*pa.x + qa.y*pa.y + qa.z*pa.z + qa.w*pa.w
               + qb.x*pb.x + qb.y*pb.y + qb.z*pb.z + qb.w*pb.w;
        }
        if (sr < NSEQ - 1) {
            float4 na = *(const float4*)(Kr + QKV_STRIDE);
            float4 nb = *(const float4*)(Kr + QKV_STRIDE + 4);
            s2 = qa.x*na.x + qa.y*na.y + qa.z*na.z + qa.w*na.w
               + qb.x*nb.x + qb.y*nb.y + qb.z*nb.z + qb.w*nb.w;
        }
#pragma unroll
        for (int off = 1; off <= 4; off <<= 1) {
            s0 += __shfl_xor(s0, off);
            s1 += __shfl_xor(s1, off);
            s2 += __shfl_xor(s2, off);
        }
        const float m  = fmaxf(fmaxf(s0, s1), fmaxf(s2, 0.f));
        const float e0 = __expf(s0 - m);
        const float e1 = __expf(s1 - m);
        const float e2 = __expf(s2 - m);
        const float eb = __expf(-m);
        const float rd = 1.f / (e0 + e1 + e2 + (float)(NSEQ - 3) * eb);
        const int h = lane >> 3, jj = lane & 7;
        const float coef = (jj == 0) ? e0 : (jj == 1) ? e1 : (jj == 2) ? e2 : eb;
        if (jj < 4) E[rl][h * 4 + jj] = coef * rd;
    }
    __syncthreads();

    // phase B: thread t -> output cols 2t, 2t+1 for all 16 rows
    const int j0 = threadIdx.x * 2;
    const float* WTb = WT + (size_t)b * 512 * 32;
    float w0[32], w1[32];
#pragma unroll
    for (int s = 0; s < 32; ++s) {
        w0[s] = WTb[(size_t)j0 * 32 + s];
        w1[s] = WTb[(size_t)(j0 + 1) * 32 + s];
    }
    const float b0 = bo[j0], b1 = bo[j0 + 1];
#pragma unroll
    for (int rl = 0; rl < 16; ++rl) {
        float a0 = b0, a1 = b1;
#pragma unroll
        for (int s = 0; s < 32; ++s) {
            const float e = E[rl][s];
            a0 = fmaf(e, w0[s], a0);
            a1 = fmaf(e, w1[s], a1);
        }
        float2 o = make_float2(a0, a1);
        *(float2*)(out + (size_t)(r0 + rl) * EMBED + j0) = o;
    }
}

extern "C" void kernel_launch(void* const* d_in, const int* in_sizes, int n_in,
                              void* d_out, int out_size, void* d_ws, size_t ws_size,
                              hipStream_t stream)
{
    const float* x  = (const float*)d_in[0];
    const float* Wq = (const float*)d_in[1];
    const float* bq = (const float*)d_in[2];
    const float* Wk = (const float*)d_in[3];
    const float* bk = (const float*)d_in[4];
    const float* Wv = (const float*)d_in[5];
    const float* bv = (const float*)d_in[6];
    const float* Wo = (const float*)d_in[7];
    const float* bo = (const float*)d_in[8];
    float* out = (float*)d_out;

    float* QKV  = (float*)d_ws;                                // 6291456 f
    u16*   xb   = (u16*)(QKV + (size_t)NROWS * QKV_STRIDE);    // 2097152 bf16
    u16*   Wcat = xb + XELEMS;                                 // 786432 bf16
    float* vs   = (float*)(Wcat + WCATELEMS);                  // 2*512 f
    float* WT   = vs + 1024;                                   // 2*512*32 f

    prep_kernel<<<NCONVB + 1, 256, 0, stream>>>(x, Wq, Wk, Wv, bv, xb, Wcat, vs);
    gemm_qkv_mfma<<<768, 256, 0, stream>>>(xb, Wcat, bq, bk, bv, QKV, vs);
    wsmall_kernel<<<128, 256, 0, stream>>>(QKV, vs, Wo, WT);
    attn_out_kernel<<<256, 256, 0, stream>>>(QKV, WT, bo, out);
}

// Round 6
// 107.876 us; speedup vs baseline: 3.6515x; 1.0081x over previous
//
#include <hip/hip_runtime.h>
#include <hip/hip_bf16.h>

#define EMBED 512
#define NSEQ 2048
#define NROWS 4096
#define QKV_STRIDE 1536

typedef unsigned short u16;
typedef __bf16 bf16x8 __attribute__((ext_vector_type(8)));
typedef float f32x4 __attribute__((ext_vector_type(4)));

__device__ __forceinline__ u16 f2bf(float f) {
    unsigned u = __float_as_uint(f);
    unsigned r = (u + 0x7FFFu + ((u >> 16) & 1u)) >> 16;
    return (u16)r;
}

#define XELEMS    (NROWS * EMBED)     // 2097152
#define WCATELEMS (1536 * EMBED)      // 786432
#define NCONVB    1408                // (XELEMS+WCATELEMS)/8/256

// ---------------------------------------------------------------------------
// prep: x -> bf16, Wq|Wk|Wv -> Wcat bf16; init vs[b][c] = 2048*bv[c]
// ---------------------------------------------------------------------------
__global__ __launch_bounds__(256) void prep_kernel(
    const float* __restrict__ x,
    const float* __restrict__ Wq, const float* __restrict__ Wk,
    const float* __restrict__ Wv, const float* __restrict__ bv,
    u16* __restrict__ xb, u16* __restrict__ Wcat, float* __restrict__ vs)
{
    if (blockIdx.x == NCONVB) {
#pragma unroll
        for (int i = 0; i < 4; ++i) {
            const int idx = threadIdx.x + i * 256;     // 0..1023 = [b][c]
            vs[idx] = (float)NSEQ * bv[idx & 511];
        }
        return;
    }
    const long long e0 = (long long)(blockIdx.x * 256 + threadIdx.x) * 8;
    const float* src;
    u16* dst;
    if (e0 < XELEMS) {
        src = x + e0; dst = xb + e0;
    } else {
        const long long j = e0 - XELEMS;
        const int row = (int)(j >> 9);
        const int col = (int)(j & 511);
        const int sel = row >> 9;            // 0:Wq 1:Wk 2:Wv
        const int r   = row & 511;
        const float* W = (sel == 0) ? Wq : (sel == 1) ? Wk : Wv;
        src = W + (size_t)r * EMBED + col; dst = Wcat + j;
    }
    float4 a = *(const float4*)(src);
    float4 b = *(const float4*)(src + 4);
    union { u16 u[8]; uint4 v; } p;
    p.u[0] = f2bf(a.x); p.u[1] = f2bf(a.y); p.u[2] = f2bf(a.z); p.u[3] = f2bf(a.w);
    p.u[4] = f2bf(b.x); p.u[5] = f2bf(b.y); p.u[6] = f2bf(b.z); p.u[7] = f2bf(b.w);
    *(uint4*)(dst) = p.v;
}

// ---------------------------------------------------------------------------
// QKV GEMM: 768 blocks, one 128x64 tile each. BK=64, XOR-swizzled LDS:
// lane fetches global k-granule (lane&7)^(lane>>3), so LDS[row][p] holds
// global granule p^(row&7); fragment reads use granule (kk*4+qd)^(lr&7)
// -> 2-way bank aliasing (free) instead of 4-way. 8 K-iterations, 16 MFMA
// per barrier pair.
// Q,K tiles: full fp32 store (+bias). V tiles: store rows 0..2 per batch
// (+bias) and atomicAdd pre-bias column sums into vs[batch][col].
// ---------------------------------------------------------------------------
__global__ __launch_bounds__(256) void gemm_qkv_mfma(
    const u16* __restrict__ A, const u16* __restrict__ W,
    const float* __restrict__ bq, const float* __restrict__ bk,
    const float* __restrict__ bvv, float* __restrict__ QKV,
    float* __restrict__ vs)
{
    __shared__ __align__(16) u16 As[128 * 64];   // 16 KB
    __shared__ __align__(16) u16 Bs[64 * 64];    // 8 KB

    const int m0 = (blockIdx.x & 31) * 128;
    const int n0 = (blockIdx.x >> 5) * 64;             // 0..1472
    const int sel = n0 >> 9;
    const float* bias = ((sel == 0) ? bq : (sel == 1) ? bk : bvv) + (n0 & 511);

    const int t    = threadIdx.x;
    const int wave = t >> 6, lane = t & 63;
    const int wm   = wave >> 1, wn = wave & 1;
    const int qd   = lane >> 4, lr = lane & 15;

    const int sr8 = lane >> 3;                 // row-in-8 for staging
    const int sg  = (lane & 7) ^ sr8;          // swizzled global granule
    const int soff = sg * 8;                   // global k offset (elems)

    f32x4 acc[4][2] = {};

    const u16* Ag = A + (size_t)m0 * EMBED;
    const u16* Wg = W + (size_t)n0 * EMBED;

    // wave-uniform LDS bases (elems); lane offset lane*16B is implicit
    u16* Adst = As + (size_t)(wave * 8) * 64;
    u16* Bdst = Bs + (size_t)(wave * 8) * 64;
    const u16* Asrc = Ag + (size_t)(wave * 8 + sr8) * EMBED + soff;
    const u16* Bsrc = Wg + (size_t)(wave * 8 + sr8) * EMBED + soff;

    for (int kc = 0; kc < EMBED; kc += 64) {
#pragma unroll
        for (int j = 0; j < 4; ++j)
            __builtin_amdgcn_global_load_lds(
                (const __attribute__((address_space(1))) void*)(Asrc + kc + (size_t)j * 32 * EMBED),
                (__attribute__((address_space(3))) void*)(Adst + j * 32 * 64), 16, 0, 0);
#pragma unroll
        for (int j = 0; j < 2; ++j)
            __builtin_amdgcn_global_load_lds(
                (const __attribute__((address_space(1))) void*)(Bsrc + kc + (size_t)j * 32 * EMBED),
                (__attribute__((address_space(3))) void*)(Bdst + j * 32 * 64), 16, 0, 0);
        __syncthreads();

#pragma unroll
        for (int kk = 0; kk < 2; ++kk) {
            const int gr = ((kk * 4 + qd) ^ (lr & 7)) * 8;
            bf16x8 af[4], bfr[2];
#pragma unroll
            for (int i = 0; i < 4; ++i)
                af[i]  = *(const bf16x8*)&As[(wm * 64 + i * 16 + lr) * 64 + gr];
#pragma unroll
            for (int i = 0; i < 2; ++i)
                bfr[i] = *(const bf16x8*)&Bs[(wn * 32 + i * 16 + lr) * 64 + gr];
#pragma unroll
            for (int mi = 0; mi < 4; ++mi)
#pragma unroll
                for (int ni = 0; ni < 2; ++ni)
                    acc[mi][ni] = __builtin_amdgcn_mfma_f32_16x16x32_bf16(
                        af[mi], bfr[ni], acc[mi][ni], 0, 0, 0);
        }
        __syncthreads();
    }

    // C/D layout: col=lane&15, row=(lane>>4)*4+reg
    if (sel < 2) {
#pragma unroll
        for (int ni = 0; ni < 2; ++ni) {
            const int cl = wn * 32 + ni * 16 + lr;
            const float bb = bias[cl];
#pragma unroll
            for (int mi = 0; mi < 4; ++mi)
#pragma unroll
                for (int e = 0; e < 4; ++e) {
                    const int row = m0 + wm * 64 + mi * 16 + qd * 4 + e;
                    QKV[(size_t)row * QKV_STRIDE + n0 + cl] = acc[mi][ni][e] + bb;
                }
        }
    } else {
        const int batch = m0 >> 11;     // tile never crosses batch (2048%128==0)
#pragma unroll
        for (int ni = 0; ni < 2; ++ni) {
            const int cl  = wn * 32 + ni * 16 + lr;
            const int col = n0 + cl;                 // 1024..1535
            const float bb = bias[cl];
            float s = 0.f;
#pragma unroll
            for (int mi = 0; mi < 4; ++mi)
#pragma unroll
                for (int e = 0; e < 4; ++e) {
                    const int row = m0 + wm * 64 + mi * 16 + qd * 4 + e;
                    s += acc[mi][ni][e];
                    if ((row & (NSEQ - 1)) < 3)
                        QKV[(size_t)row * QKV_STRIDE + col] = acc[mi][ni][e] + bb;
                }
            s += __shfl_xor(s, 16);
            s += __shfl_xor(s, 32);
            if (qd == 0)
                atomicAdd(&vs[batch * 512 + (col - 1024)], s);
        }
    }
}

// ---------------------------------------------------------------------------
// Wsmall: WT[b][j][s] (s=4h+t) = sum_{c in head h} Vsm[b][t][c] * Wo[j][c]
// Vsm rows: t=0,1,2 -> V rows 0..2 (biased, from QKV); t=3 -> tail sum.
// Grid 128 blocks (2 batches x 64 j-groups of 8).
// ---------------------------------------------------------------------------
__global__ __launch_bounds__(256) void wsmall_kernel(
    const float* __restrict__ QKV, const float* __restrict__ vs,
    const float* __restrict__ Wo, float* __restrict__ WT)
{
    __shared__ float Vsm[4][512];
    const int b  = blockIdx.x >> 6;
    const int jb = blockIdx.x & 63;
    const int t  = threadIdx.x;

    const float* Vbase = QKV + (size_t)b * NSEQ * QKV_STRIDE + 1024;
    for (int idx = t; idx < 512; idx += 256) {
        const float v0 = Vbase[idx];
        const float v1 = Vbase[QKV_STRIDE + idx];
        const float v2 = Vbase[2 * QKV_STRIDE + idx];
        Vsm[0][idx] = v0; Vsm[1][idx] = v1; Vsm[2][idx] = v2;
        Vsm[3][idx] = vs[b * 512 + idx] - (v0 + v1 + v2);
    }
    __syncthreads();

    const int j  = jb * 8 + (t >> 5);
    const int s  = t & 31;
    const int h  = s >> 2, tt = s & 3;
    const float* Wor = Wo + (size_t)j * EMBED + h * 64;
    const float* vr  = &Vsm[tt][h * 64];
    float acc = 0.f;
#pragma unroll
    for (int c = 0; c < 64; ++c) {
        const int cc = (c + 2 * s) & 63;    // rotate to spread LDS banks
        acc = fmaf(vr[cc], Wor[cc], acc);
    }
    WT[((size_t)b * 512 + j) * 32 + s] = acc;
}

// ---------------------------------------------------------------------------
// Fused attention + K=32 output GEMM. Grid 256 blocks x 16 rows.
// ---------------------------------------------------------------------------
__global__ __launch_bounds__(256) void attn_out_kernel(
    const float* __restrict__ QKV, const float* __restrict__ WT,
    const float* __restrict__ bo, float* __restrict__ out)
{
    __shared__ float E[16][32];
    const int r0   = blockIdx.x * 16;
    const int b    = r0 >> 11;
    const int wave = threadIdx.x >> 6, lane = threadIdx.x & 63;
    const int d0   = lane * 8;

#pragma unroll
    for (int i = 0; i < 4; ++i) {
        const int rl = wave * 4 + i;
        const int r  = r0 + rl;
        const int sr = r & (NSEQ - 1);
        const float* Qr = QKV + (size_t)r * QKV_STRIDE + d0;
        const float* Kr = QKV + (size_t)r * QKV_STRIDE + 512 + d0;

        float4 qa = *(const float4*)(Qr);
        float4 qb = *(const float4*)(Qr + 4);
        float4 ka = *(const float4*)(Kr);
        float4 kb = *(const float4*)(Kr + 4);
        float s1 = qa.x*ka.x + qa.y*ka.y + qa.z*ka.z + qa.w*ka.w
                 + qb.x*kb.x + qb.y*kb.y + qb.z*kb.z + qb.w*kb.w;
        float s0 = 0.f, s2 = 0.f;
        if (sr > 0) {
            float4 pa = *(const float4*)(Kr - QKV_STRIDE);
            float4 pb = *(const float4*)(Kr - QKV_STRIDE + 4);
            s0 = qa.x*pa.x + qa.y*pa.y + qa.z*pa.z + qa.w*pa.w
               + qb.x*pb.x + qb.y*pb.y + qb.z*pb.z + qb.w*pb.w;
        }
        if (sr < NSEQ - 1) {
            float4 na = *(const float4*)(Kr + QKV_STRIDE);
            float4 nb = *(const float4*)(Kr + QKV_STRIDE + 4);
            s2 = qa.x*na.x + qa.y*na.y + qa.z*na.z + qa.w*na.w
               + qb.x*nb.x + qb.y*nb.y + qb.z*nb.z + qb.w*nb.w;
        }
#pragma unroll
        for (int off = 1; off <= 4; off <<= 1) {
            s0 += __shfl_xor(s0, off);
            s1 += __shfl_xor(s1, off);
            s2 += __shfl_xor(s2, off);
        }
        const float m  = fmaxf(fmaxf(s0, s1), fmaxf(s2, 0.f));
        const float e0 = __expf(s0 - m);
        const float e1 = __expf(s1 - m);
        const float e2 = __expf(s2 - m);
        const float eb = __expf(-m);
        const float rd = 1.f / (e0 + e1 + e2 + (float)(NSEQ - 3) * eb);
        const int h = lane >> 3, jj = lane & 7;
        const float coef = (jj == 0) ? e0 : (jj == 1) ? e1 : (jj == 2) ? e2 : eb;
        if (jj < 4) E[rl][h * 4 + jj] = coef * rd;
    }
    __syncthreads();

    const int j0 = threadIdx.x * 2;
    const float* WTb = WT + (size_t)b * 512 * 32;
    float w0[32], w1[32];
#pragma unroll
    for (int s = 0; s < 32; ++s) {
        w0[s] = WTb[(size_t)j0 * 32 + s];
        w1[s] = WTb[(size_t)(j0 + 1) * 32 + s];
    }
    const float b0 = bo[j0], b1 = bo[j0 + 1];
#pragma unroll
    for (int rl = 0; rl < 16; ++rl) {
        float a0 = b0, a1 = b1;
#pragma unroll
        for (int s = 0; s < 32; ++s) {
            const float e = E[rl][s];
            a0 = fmaf(e, w0[s], a0);
            a1 = fmaf(e, w1[s], a1);
        }
        float2 o = make_float2(a0, a1);
        *(float2*)(out + (size_t)(r0 + rl) * EMBED + j0) = o;
    }
}

extern "C" void kernel_launch(void* const* d_in, const int* in_sizes, int n_in,
                              void* d_out, int out_size, void* d_ws, size_t ws_size,
                              hipStream_t stream)
{
    const float* x  = (const float*)d_in[0];
    const float* Wq = (const float*)d_in[1];
    const float* bq = (const float*)d_in[2];
    const float* Wk = (const float*)d_in[3];
    const float* bk = (const float*)d_in[4];
    const float* Wv = (const float*)d_in[5];
    const float* bv = (const float*)d_in[6];
    const float* Wo = (const float*)d_in[7];
    const float* bo = (const float*)d_in[8];
    float* out = (float*)d_out;

    float* QKV  = (float*)d_ws;                                // 6291456 f
    u16*   xb   = (u16*)(QKV + (size_t)NROWS * QKV_STRIDE);    // 2097152 bf16
    u16*   Wcat = xb + XELEMS;                                 // 786432 bf16
    float* vs   = (float*)(Wcat + WCATELEMS);                  // 2*512 f
    float* WT   = vs + 1024;                                   // 2*512*32 f

    prep_kernel<<<NCONVB + 1, 256, 0, stream>>>(x, Wq, Wk, Wv, bv, xb, Wcat, vs);
    gemm_qkv_mfma<<<768, 256, 0, stream>>>(xb, Wcat, bq, bk, bv, QKV, vs);
    wsmall_kernel<<<128, 256, 0, stream>>>(QKV, vs, Wo, WT);
    attn_out_kernel<<<256, 256, 0, stream>>>(QKV, WT, bo, out);
}

// Round 7
// 105.507 us; speedup vs baseline: 3.7335x; 1.0225x over previous
//
#include <hip/hip_runtime.h>
#include <hip/hip_bf16.h>

#define EMBED 512
#define NSEQ 2048
#define NROWS 4096

typedef unsigned short u16;
typedef __bf16 bf16x8 __attribute__((ext_vector_type(8)));
typedef float f32x4 __attribute__((ext_vector_type(4)));
typedef unsigned short ushort8 __attribute__((ext_vector_type(8)));

__device__ __forceinline__ u16 f2bf(float f) {
    unsigned u = __float_as_uint(f);
    unsigned r = (u + 0x7FFFu + ((u >> 16) & 1u)) >> 16;
    return (u16)r;
}
__device__ __forceinline__ float bf2f(u16 v) {
    return __uint_as_float((unsigned)v << 16);
}

#define XELEMS    (NROWS * EMBED)     // 2097152
#define WCATELEMS (1536 * EMBED)      // 786432
#define NCONVB    1408                // (XELEMS+WCATELEMS)/8/256

// ---------------------------------------------------------------------------
// prep: x -> bf16, Wq|Wk|Wv -> Wcat bf16.
// ---------------------------------------------------------------------------
__global__ __launch_bounds__(256) void prep_kernel(
    const float* __restrict__ x,
    const float* __restrict__ Wq, const float* __restrict__ Wk,
    const float* __restrict__ Wv,
    u16* __restrict__ xb, u16* __restrict__ Wcat)
{
    const long long e0 = (long long)(blockIdx.x * 256 + threadIdx.x) * 8;
    const float* src;
    u16* dst;
    if (e0 < XELEMS) {
        src = x + e0; dst = xb + e0;
    } else {
        const long long j = e0 - XELEMS;
        const int row = (int)(j >> 9);
        const int col = (int)(j & 511);
        const int sel = row >> 9;            // 0:Wq 1:Wk 2:Wv
        const int r   = row & 511;
        const float* W = (sel == 0) ? Wq : (sel == 1) ? Wk : Wv;
        src = W + (size_t)r * EMBED + col; dst = Wcat + j;
    }
    float4 a = *(const float4*)(src);
    float4 b = *(const float4*)(src + 4);
    union { u16 u[8]; uint4 v; } p;
    p.u[0] = f2bf(a.x); p.u[1] = f2bf(a.y); p.u[2] = f2bf(a.z); p.u[3] = f2bf(a.w);
    p.u[4] = f2bf(b.x); p.u[5] = f2bf(b.y); p.u[6] = f2bf(b.z); p.u[7] = f2bf(b.w);
    *(uint4*)(dst) = p.v;
}

// ---------------------------------------------------------------------------
// QKV GEMM: 768 blocks, one 128x64 tile each. BK=64, XOR-swizzled LDS
// (2-way bank aliasing on fragment reads = free).
// Q,K tiles (sel<2): store bf16 into QKb[row][col] (col 0..1023).
// V tiles (sel==2): store rows 0..2 per batch into Vhead (fp32, +bias) and
// write per-(col, mtile, wm) pre-bias column sums into write-once vpart slots.
// ---------------------------------------------------------------------------
__global__ __launch_bounds__(256) void gemm_qkv_mfma(
    const u16* __restrict__ A, const u16* __restrict__ W,
    const float* __restrict__ bq, const float* __restrict__ bk,
    const float* __restrict__ bvv,
    u16* __restrict__ QKb, float* __restrict__ Vhead,
    float* __restrict__ vpart)
{
    __shared__ __align__(16) u16 As[128 * 64];   // 16 KB
    __shared__ __align__(16) u16 Bs[64 * 64];    // 8 KB

    const int m0 = (blockIdx.x & 31) * 128;
    const int n0 = (blockIdx.x >> 5) * 64;             // 0..1472
    const int sel = n0 >> 9;
    const float* bias = ((sel == 0) ? bq : (sel == 1) ? bk : bvv) + (n0 & 511);

    const int t    = threadIdx.x;
    const int wave = t >> 6, lane = t & 63;
    const int wm   = wave >> 1, wn = wave & 1;
    const int qd   = lane >> 4, lr = lane & 15;

    const int sr8 = lane >> 3;                 // row-in-8 for staging
    const int sg  = (lane & 7) ^ sr8;          // swizzled global granule
    const int soff = sg * 8;                   // global k offset (elems)

    f32x4 acc[4][2] = {};

    const u16* Ag = A + (size_t)m0 * EMBED;
    const u16* Wg = W + (size_t)n0 * EMBED;

    u16* Adst = As + (size_t)(wave * 8) * 64;
    u16* Bdst = Bs + (size_t)(wave * 8) * 64;
    const u16* Asrc = Ag + (size_t)(wave * 8 + sr8) * EMBED + soff;
    const u16* Bsrc = Wg + (size_t)(wave * 8 + sr8) * EMBED + soff;

    for (int kc = 0; kc < EMBED; kc += 64) {
#pragma unroll
        for (int j = 0; j < 4; ++j)
            __builtin_amdgcn_global_load_lds(
                (const __attribute__((address_space(1))) void*)(Asrc + kc + (size_t)j * 32 * EMBED),
                (__attribute__((address_space(3))) void*)(Adst + j * 32 * 64), 16, 0, 0);
#pragma unroll
        for (int j = 0; j < 2; ++j)
            __builtin_amdgcn_global_load_lds(
                (const __attribute__((address_space(1))) void*)(Bsrc + kc + (size_t)j * 32 * EMBED),
                (__attribute__((address_space(3))) void*)(Bdst + j * 32 * 64), 16, 0, 0);
        __syncthreads();

#pragma unroll
        for (int kk = 0; kk < 2; ++kk) {
            const int gr = ((kk * 4 + qd) ^ (lr & 7)) * 8;
            bf16x8 af[4], bfr[2];
#pragma unroll
            for (int i = 0; i < 4; ++i)
                af[i]  = *(const bf16x8*)&As[(wm * 64 + i * 16 + lr) * 64 + gr];
#pragma unroll
            for (int i = 0; i < 2; ++i)
                bfr[i] = *(const bf16x8*)&Bs[(wn * 32 + i * 16 + lr) * 64 + gr];
#pragma unroll
            for (int mi = 0; mi < 4; ++mi)
#pragma unroll
                for (int ni = 0; ni < 2; ++ni)
                    acc[mi][ni] = __builtin_amdgcn_mfma_f32_16x16x32_bf16(
                        af[mi], bfr[ni], acc[mi][ni], 0, 0, 0);
        }
        __syncthreads();
    }

    // C/D layout: col=lane&15, row=(lane>>4)*4+reg
    if (sel < 2) {
#pragma unroll
        for (int ni = 0; ni < 2; ++ni) {
            const int cl = wn * 32 + ni * 16 + lr;
            const float bb = bias[cl];
#pragma unroll
            for (int mi = 0; mi < 4; ++mi)
#pragma unroll
                for (int e = 0; e < 4; ++e) {
                    const int row = m0 + wm * 64 + mi * 16 + qd * 4 + e;
                    QKb[(size_t)row * 1024 + n0 + cl] = f2bf(acc[mi][ni][e] + bb);
                }
        }
    } else {
        const int batch = m0 >> 11;          // tile never crosses batch
        const int mtb   = (m0 >> 7) & 15;    // m-tile within batch
#pragma unroll
        for (int ni = 0; ni < 2; ++ni) {
            const int cl  = wn * 32 + ni * 16 + lr;
            const int col = (n0 - 1024) + cl;            // 0..511
            const float bb = bias[cl];
            float s = 0.f;
#pragma unroll
            for (int mi = 0; mi < 4; ++mi)
#pragma unroll
                for (int e = 0; e < 4; ++e) {
                    const int row = m0 + wm * 64 + mi * 16 + qd * 4 + e;
                    s += acc[mi][ni][e];
                    if ((row & (NSEQ - 1)) < 3)
                        Vhead[(size_t)batch * 1536 + (row & (NSEQ - 1)) * 512 + col]
                            = acc[mi][ni][e] + bb;
                }
            s += __shfl_xor(s, 16);
            s += __shfl_xor(s, 32);
            if (qd == 0)   // one slot per (batch,col,mtb,wm): written exactly once
                vpart[((size_t)batch * 512 + col) * 32 + mtb * 2 + wm] = s;
        }
    }
}

// ---------------------------------------------------------------------------
// Wsmall: WT[b][j][s] (s=4h+t) = sum_{c in head h} Vsm[b][t][c] * Wo[j][c]
// Vsm t=0,1,2 -> Vhead rows (biased); t=3 -> tail = sum32(vpart) + 2048*bv
// - (v0+v1+v2). Grid 128 blocks (2 batches x 64 j-groups of 8).
// ---------------------------------------------------------------------------
__global__ __launch_bounds__(256) void wsmall_kernel(
    const float* __restrict__ Vhead, const float* __restrict__ vpart,
    const float* __restrict__ bv,
    const float* __restrict__ Wo, float* __restrict__ WT)
{
    __shared__ float Vsm[4][512];
    const int b  = blockIdx.x >> 6;
    const int jb = blockIdx.x & 63;
    const int t  = threadIdx.x;

    for (int idx = t; idx < 512; idx += 256) {
        const float v0 = Vhead[(size_t)b * 1536 + idx];
        const float v1 = Vhead[(size_t)b * 1536 + 512 + idx];
        const float v2 = Vhead[(size_t)b * 1536 + 1024 + idx];
        float sum = 0.f;
        const float* vp = vpart + ((size_t)b * 512 + idx) * 32;
#pragma unroll
        for (int s = 0; s < 32; ++s) sum += vp[s];
        Vsm[0][idx] = v0; Vsm[1][idx] = v1; Vsm[2][idx] = v2;
        Vsm[3][idx] = sum + (float)NSEQ * bv[idx] - (v0 + v1 + v2);
    }
    __syncthreads();

    const int j  = jb * 8 + (t >> 5);
    const int s  = t & 31;
    const int h  = s >> 2, tt = s & 3;
    const float* Wor = Wo + (size_t)j * EMBED + h * 64;
    const float* vr  = &Vsm[tt][h * 64];
    float acc = 0.f;
#pragma unroll
    for (int c = 0; c < 64; ++c) {
        const int cc = (c + 2 * s) & 63;    // rotate to spread LDS banks
        acc = fmaf(vr[cc], Wor[cc], acc);
    }
    WT[((size_t)b * 512 + j) * 32 + s] = acc;
}

// ---------------------------------------------------------------------------
// Fused attention + K=32 output GEMM. Grid 256 blocks x 16 rows.
// Q,K read as bf16 (16B/lane loads), dots in fp32.
// ---------------------------------------------------------------------------
__global__ __launch_bounds__(256) void attn_out_kernel(
    const u16* __restrict__ QKb, const float* __restrict__ WT,
    const float* __restrict__ bo, float* __restrict__ out)
{
    __shared__ float E[16][32];
    const int r0   = blockIdx.x * 16;
    const int b    = r0 >> 11;
    const int wave = threadIdx.x >> 6, lane = threadIdx.x & 63;
    const int d0   = lane * 8;

#pragma unroll
    for (int i = 0; i < 4; ++i) {
        const int rl = wave * 4 + i;
        const int r  = r0 + rl;
        const int sr = r & (NSEQ - 1);
        const u16* Qr = QKb + (size_t)r * 1024 + d0;
        const u16* Kr = QKb + (size_t)r * 1024 + 512 + d0;

        ushort8 qv = *(const ushort8*)Qr;
        ushort8 kv = *(const ushort8*)Kr;
        float q[8], k[8];
#pragma unroll
        for (int z = 0; z < 8; ++z) { q[z] = bf2f(qv[z]); k[z] = bf2f(kv[z]); }

        float s1 = 0.f;
#pragma unroll
        for (int z = 0; z < 8; ++z) s1 = fmaf(q[z], k[z], s1);

        float s0 = 0.f, s2 = 0.f;
        if (sr > 0) {
            ushort8 pv = *(const ushort8*)(Kr - 1024);
#pragma unroll
            for (int z = 0; z < 8; ++z) s0 = fmaf(q[z], bf2f(pv[z]), s0);
        }
        if (sr < NSEQ - 1) {
            ushort8 nv = *(const ushort8*)(Kr + 1024);
#pragma unroll
            for (int z = 0; z < 8; ++z) s2 = fmaf(q[z], bf2f(nv[z]), s2);
        }
#pragma unroll
        for (int off = 1; off <= 4; off <<= 1) {
            s0 += __shfl_xor(s0, off);
            s1 += __shfl_xor(s1, off);
            s2 += __shfl_xor(s2, off);
        }
        const float m  = fmaxf(fmaxf(s0, s1), fmaxf(s2, 0.f));
        const float e0 = __expf(s0 - m);
        const float e1 = __expf(s1 - m);
        const float e2 = __expf(s2 - m);
        const float eb = __expf(-m);
        const float rd = 1.f / (e0 + e1 + e2 + (float)(NSEQ - 3) * eb);
        const int h = lane >> 3, jj = lane & 7;
        const float coef = (jj == 0) ? e0 : (jj == 1) ? e1 : (jj == 2) ? e2 : eb;
        if (jj < 4) E[rl][h * 4 + jj] = coef * rd;
    }
    __syncthreads();

    const int j0 = threadIdx.x * 2;
    const float* WTb = WT + (size_t)b * 512 * 32;
    float w0[32], w1[32];
#pragma unroll
    for (int s = 0; s < 32; ++s) {
        w0[s] = WTb[(size_t)j0 * 32 + s];
        w1[s] = WTb[(size_t)(j0 + 1) * 32 + s];
    }
    const float b0 = bo[j0], b1 = bo[j0 + 1];
#pragma unroll
    for (int rl = 0; rl < 16; ++rl) {
        float a0 = b0, a1 = b1;
#pragma unroll
        for (int s = 0; s < 32; ++s) {
            const float e = E[rl][s];
            a0 = fmaf(e, w0[s], a0);
            a1 = fmaf(e, w1[s], a1);
        }
        float2 o = make_float2(a0, a1);
        *(float2*)(out + (size_t)(r0 + rl) * EMBED + j0) = o;
    }
}

extern "C" void kernel_launch(void* const* d_in, const int* in_sizes, int n_in,
                              void* d_out, int out_size, void* d_ws, size_t ws_size,
                              hipStream_t stream)
{
    const float* x  = (const float*)d_in[0];
    const float* Wq = (const float*)d_in[1];
    const float* bq = (const float*)d_in[2];
    const float* Wk = (const float*)d_in[3];
    const float* bk = (const float*)d_in[4];
    const float* Wv = (const float*)d_in[5];
    const float* bv = (const float*)d_in[6];
    const float* Wo = (const float*)d_in[7];
    const float* bo = (const float*)d_in[8];
    float* out = (float*)d_out;

    u16*   QKb   = (u16*)d_ws;                     // 4096*1024 u16 (Q|K bf16)
    u16*   xb    = QKb + (size_t)NROWS * 1024;     // 2097152 bf16
    u16*   Wcat  = xb + XELEMS;                    // 786432 bf16
    float* Vhead = (float*)(Wcat + WCATELEMS);     // 2*3*512 f32
    float* vpart = Vhead + 2 * 3 * 512;            // 2*512*32 f32 (write-once)
    float* WT    = vpart + 2 * 512 * 32;           // 2*512*32 f32

    prep_kernel<<<NCONVB, 256, 0, stream>>>(x, Wq, Wk, Wv, xb, Wcat);
    gemm_qkv_mfma<<<768, 256, 0, stream>>>(xb, Wcat, bq, bk, bv, QKb, Vhead, vpart);
    wsmall_kernel<<<128, 256, 0, stream>>>(Vhead, vpart, bv, Wo, WT);
    attn_out_kernel<<<256, 256, 0, stream>>>(QKb, WT, bo, out);
}